// Round 1
// baseline (405.414 us; speedup 1.0000x reference)
//
#include <hip/hip_runtime.h>
#include <cstdint>
#include <cstddef>

// LIF recurrent SNN, sinabs ThresholdSubtract.
//   B=32 independent batch rows -> 1 block per batch, state in registers.
//   Spikes ~4.4 sigma -> speculate "no spike in chunk", exact replay on hit.
// Round-8: x-prefetch via global_load_lds DMA into a 4-slot LDS ring.
//   LEDGER R1..R7: every register-destination prefetch (plain loads R6/R7,
//   asm loads R2/R5, arrays R1) was defeated -- the pre-RA scheduler +
//   MachineSink re-sink loads to their single use (VGPR_Count 68 < the 96
//   needed for 3 live Chunk buffers proves it), giving 8 serialized ~420cy
//   L3 hits/chunk = 3340cy/chunk = 174us. R4's LDS-DMA failed differently:
//   compiler-visible ds_reads of the DMA target force vmcnt(0) per chunk.
//   R8 fixes both: DMA has NO dest VGPRs (nothing to sink), and the x-buffer
//   is consumed ONLY via inline-asm ds_read_b128 (invisible to the waitcnt
//   pass), ordered by hand-counted vmcnt(24/16/8/0) + lgkmcnt(0) +
//   sched_barrier(0). Wave w DMAs and reads exactly segment w of each row
//   (tid*16B == wv*1024B + lane*16B), so per-wave vmcnt counting is sound
//   and the per-chunk s_barrier needs no vmcnt drain.
#define B_       32
#define T_       1000
#define N_       1024
#define THREADS_ 256           // 4 waves; each thread owns 4 consecutive neurons
#define WAVES_   4
#define CHUNK_   8
#define NCHUNK_  125           // 125*8 = 1000 steps
#define DEPTH_   4             // LDS ring slots (prefetch distance 3)
#define SLOT_BYTES_ 32768      // CHUNK_*N_*4
#define ZBLOCKS_ 2048

typedef float v4f __attribute__((ext_vector_type(4)));
typedef __attribute__((address_space(1))) const void gc_void;
typedef __attribute__((address_space(3))) void lds_void;

// Barrier draining only LDS (lgkmcnt), NOT vmcnt: DMA prefetches for future
// chunks stay in flight across the per-chunk exchange barrier.
__device__ __forceinline__ void barrier_lds() {
  __asm__ volatile("s_waitcnt lgkmcnt(0)\n\ts_barrier" ::: "memory");
}

__device__ __forceinline__ v4f vmax4(v4f a, v4f b) {
  v4f r;
  r.x = fmaxf(a.x, b.x); r.y = fmaxf(a.y, b.y);
  r.z = fmaxf(a.z, b.z); r.w = fmaxf(a.w, b.w);
  return r;
}

// Inline-asm LDS read: opaque to SIInsertWaitcnts (no auto vmcnt/lgkm waits,
// no LDS-DMA alias analysis). We order it manually.
#define DSRD(dst, base, imm)                                                 \
  asm volatile("ds_read_b128 %0, %1 offset:" #imm : "=v"(dst) : "v"(base))

// Issue one chunk's 8 row-DMAs for this wave's 1KB segment of each 4KB row.
// HW writes lane l's 16B at lds_base + l*16; lane l supplies the matching
// per-lane global address (xg already includes tid*4 floats).
#define ISSUE_DMA(cc)                                                        \
  do {                                                                       \
    const float* _g = xg + (size_t)(cc) * (CHUNK_ * N_);                     \
    char* _l = xls + ((cc) & (DEPTH_ - 1)) * SLOT_BYTES_;                    \
    __builtin_amdgcn_global_load_lds((gc_void*)(_g + 0 * N_), (lds_void*)(_l + 0 * 4096), 16, 0, 0); \
    __builtin_amdgcn_global_load_lds((gc_void*)(_g + 1 * N_), (lds_void*)(_l + 1 * 4096), 16, 0, 0); \
    __builtin_amdgcn_global_load_lds((gc_void*)(_g + 2 * N_), (lds_void*)(_l + 2 * 4096), 16, 0, 0); \
    __builtin_amdgcn_global_load_lds((gc_void*)(_g + 3 * N_), (lds_void*)(_l + 3 * 4096), 16, 0, 0); \
    __builtin_amdgcn_global_load_lds((gc_void*)(_g + 4 * N_), (lds_void*)(_l + 4 * 4096), 16, 0, 0); \
    __builtin_amdgcn_global_load_lds((gc_void*)(_g + 5 * N_), (lds_void*)(_l + 5 * 4096), 16, 0, 0); \
    __builtin_amdgcn_global_load_lds((gc_void*)(_g + 6 * N_), (lds_void*)(_l + 6 * 4096), 16, 0, 0); \
    __builtin_amdgcn_global_load_lds((gc_void*)(_g + 7 * N_), (lds_void*)(_l + 7 * 4096), 16, 0, 0); \
    __builtin_amdgcn_sched_barrier(0);  /* DMA issue may not sink */         \
  } while (0)

#define SPEC_STEP(xf)                                                        \
  do {                                                                       \
    cmax = vmax4(cmax, st);                                                  \
    v4f _t = (xf) + rr;                                                      \
    st = st * 0.9f + 0.1f * _t;                                              \
    rr = brec;                                                               \
  } while (0)

// Process chunk cc from its LDS slot. VM = vmcnt immediate that guarantees
// this chunk's 8 DMAs (this wave's) have landed: 8 * (#chunks issued beyond
// cc). Speculative no-spike pass; block-wide ballot; exact replay (rare).
#define PROCESS(cc, VM)                                                      \
  do {                                                                       \
    unsigned _a = xb + (unsigned)(((cc) & (DEPTH_ - 1)) * SLOT_BYTES_)       \
                     + ((unsigned)tid << 4);                                 \
    asm volatile("s_waitcnt vmcnt(" #VM ")" ::: "memory");                   \
    v4f _x0, _x1, _x2, _x3, _x4, _x5, _x6, _x7;                              \
    DSRD(_x0, _a, 0);     DSRD(_x1, _a, 4096);                               \
    DSRD(_x2, _a, 8192);  DSRD(_x3, _a, 12288);                              \
    DSRD(_x4, _a, 16384); DSRD(_x5, _a, 20480);                              \
    DSRD(_x6, _a, 24576); DSRD(_x7, _a, 28672);                              \
    asm volatile("s_waitcnt lgkmcnt(0)" ::: "memory");                       \
    __builtin_amdgcn_sched_barrier(0);  /* rule #18: no VALU hoist above */  \
    v4f st = state, rr = rec, cmax = state;                                  \
    SPEC_STEP(_x0); SPEC_STEP(_x1); SPEC_STEP(_x2); SPEC_STEP(_x3);          \
    SPEC_STEP(_x4); SPEC_STEP(_x5); SPEC_STEP(_x6); SPEC_STEP(_x7);          \
    float _m = fmaxf(fmaxf(cmax.x, cmax.y), fmaxf(cmax.z, cmax.w));          \
    int _any = (_m >= 1.0f);                                                 \
    const int _p = (cc) & 1;                                                 \
    unsigned long long _wm = __ballot(_any);                                 \
    if (lane == 0) s_cmask[_p][wv] = _wm;                                    \
    barrier_lds();                                                           \
    unsigned long long _ab =                                                 \
        s_cmask[_p][0] | s_cmask[_p][1] | s_cmask[_p][2] | s_cmask[_p][3];   \
    if (_ab == 0ULL) { state = st; rec = brec; }                             \
    else { replay(cc); }                                                     \
  } while (0)

__global__ __launch_bounds__(THREADS_, 1)
void lif_fused(const float* __restrict__ x, const float* __restrict__ w,
               const float* __restrict__ brec_g, float* __restrict__ out,
               unsigned long long* __restrict__ ws_rec,
               unsigned int* __restrict__ ws_cnt, int cap)
{
  // ---------------- zero path: blocks >= 32 clear the output ----------------
  if (blockIdx.x >= B_) {
    const size_t n4 = (size_t)B_ * T_ * N_ / 4;
    size_t i = (size_t)(blockIdx.x - B_) * THREADS_ + threadIdx.x;
    const size_t stride = (size_t)(gridDim.x - B_) * THREADS_;
    v4f* o4 = (v4f*)out;
    v4f z = (v4f)(0.f);
    for (; i < n4; i += stride) __builtin_nontemporal_store(z, &o4[i]);
    return;
  }

  // ---------------- lif path: blocks 0..31, one batch row each --------------
  const int b    = blockIdx.x;
  const int tid  = threadIdx.x;
  const int lane = tid & 63;
  const int wv   = tid >> 6;
  const int n0   = tid << 2;

  // x staging ring: 4 slots x 32KB. Wave w owns bytes [w*1024, w*1024+1024)
  // of every 4KB row (DMA dest AND ds_read source -- no cross-wave deps).
  __shared__ v4f xbuf4[DEPTH_ * CHUNK_ * N_ / 4];
  // Parity-double-buffered exchange: one barrier per chunk/step, no resets.
  __shared__ unsigned long long s_cmask[2][WAVES_];
  __shared__ unsigned long long s_mask [2][WAVES_];
  __shared__ v4f                s_val  [2][THREADS_];
  __shared__ unsigned int       s_spkcnt;

  if (tid == 0) s_spkcnt = 0;   // ordered by the first chunk's barrier_lds

  // per-lane global column pointer (doubles as DMA source: tid*16B is
  // exactly this wave's segment byte for this lane)
  const float* xg = x + (size_t)b * T_ * N_ + n0;
  // wave-uniform LDS dest base for DMA
  char* xls = (char*)xbuf4 + (wv << 10);
  // LDS byte offset of the ring for asm ds_read
  const unsigned xb = (unsigned)(uintptr_t)(__attribute__((address_space(3))) void*)xbuf4;

  v4f state = (v4f)(0.f);
  v4f rec   = (v4f)(0.f);                 // initial carry rec = 0 (NOT b_rec)
  const v4f brec = *(const v4f*)(brec_g + n0);

  // Exact replay of chunk cc (rare): re-reads x from GLOBAL (keeps the LDS
  // ring and vmcnt bookkeeping untouched; compiler-inserted waits drain the
  // pipe, which is correct and merely refills ~1k cy). Per-step spike
  // exchange, sparse rank-1 rec update, spike records.
  auto replay = [&](int cc) {
    v4f st = state;
    v4f r  = rec;
    const float* xrep = xg + (size_t)cc * (CHUNK_ * N_);
#pragma unroll 1
    for (int k = 0; k < CHUNK_; ++k) {
      const int q = k & 1;
      v4f xv = *(const v4f*)(xrep + (size_t)k * N_);
      float tx = xv.x + r.x, ty = xv.y + r.y, tz = xv.z + r.z, tw = xv.w + r.w;
      float ax = (st.x > 0.f) ? floorf(st.x) : 0.f;
      float ay = (st.y > 0.f) ? floorf(st.y) : 0.f;
      float az = (st.z > 0.f) ? floorf(st.z) : 0.f;
      float aw = (st.w > 0.f) ? floorf(st.w) : 0.f;
      int ms = (ax != 0.f) | (ay != 0.f) | (az != 0.f) | (aw != 0.f);
      if (ms) {
        v4f v; v.x = ax; v.y = ay; v.z = az; v.w = aw;
        s_val[q][tid] = v;
        unsigned int off = (unsigned int)((cc * CHUNK_ + k) * N_ + n0);
        float av[4] = {ax, ay, az, aw};
#pragma unroll
        for (int e = 0; e < 4; ++e) {
          if (av[e] != 0.f) {
            unsigned int idx = atomicAdd(&s_spkcnt, 1u);
            if ((int)idx < cap)
              ws_rec[(size_t)b * cap + idx] =
                  ((unsigned long long)(off + e) << 32) |
                  (unsigned long long)__float_as_uint(av[e]);
          }
        }
      }
      unsigned long long sm = __ballot(ms);
      if (lane == 0) s_mask[q][wv] = sm;
      st.x = (st.x - ax) * 0.9f + 0.1f * tx;
      st.y = (st.y - ay) * 0.9f + 0.1f * ty;
      st.z = (st.z - az) * 0.9f + 0.1f * tz;
      st.w = (st.w - aw) * 0.9f + 0.1f * tw;
      barrier_lds();
      // sparse rank-1 rec update: rec[n] = b_rec[n] + sum_j act[j]*w[n][j]
      v4f racc = brec;
#pragma unroll 1
      for (int w2 = 0; w2 < WAVES_; ++w2) {
        unsigned long long mm = s_mask[q][w2];
        while (mm) {
          int l = __builtin_ctzll(mm);
          mm &= mm - 1;
          int j = (w2 << 6) + l;
          v4f v = s_val[q][j];
          int jn = j << 2;
          if (v.x != 0.f) {
            racc.x += v.x * w[(size_t)(n0 + 0) * N_ + jn];
            racc.y += v.x * w[(size_t)(n0 + 1) * N_ + jn];
            racc.z += v.x * w[(size_t)(n0 + 2) * N_ + jn];
            racc.w += v.x * w[(size_t)(n0 + 3) * N_ + jn];
          }
          if (v.y != 0.f) {
            int j1 = jn + 1;
            racc.x += v.y * w[(size_t)(n0 + 0) * N_ + j1];
            racc.y += v.y * w[(size_t)(n0 + 1) * N_ + j1];
            racc.z += v.y * w[(size_t)(n0 + 2) * N_ + j1];
            racc.w += v.y * w[(size_t)(n0 + 3) * N_ + j1];
          }
          if (v.z != 0.f) {
            int j2 = jn + 2;
            racc.x += v.z * w[(size_t)(n0 + 0) * N_ + j2];
            racc.y += v.z * w[(size_t)(n0 + 1) * N_ + j2];
            racc.z += v.z * w[(size_t)(n0 + 2) * N_ + j2];
            racc.w += v.z * w[(size_t)(n0 + 3) * N_ + j2];
          }
          if (v.w != 0.f) {
            int j3 = jn + 3;
            racc.x += v.w * w[(size_t)(n0 + 0) * N_ + j3];
            racc.y += v.w * w[(size_t)(n0 + 1) * N_ + j3];
            racc.z += v.w * w[(size_t)(n0 + 2) * N_ + j3];
            racc.w += v.w * w[(size_t)(n0 + 3) * N_ + j3];
          }
        }
      }
      r = racc;
    }
    state = st;
    rec   = r;
  };

  // ---- DMA-pipelined chunk loop: 24 loads in flight, counted vmcnt ----
  // Slot overwrite distance 3 < DEPTH_ 4; this wave's reads of the evicted
  // chunk finished at its own lgkmcnt(0) one iteration earlier.
  ISSUE_DMA(0); ISSUE_DMA(1); ISSUE_DMA(2);

#pragma unroll 1
  for (int c = 0; c < NCHUNK_ - 3; ++c) {   // chunks 0..121
    ISSUE_DMA(c + 3);
    PROCESS(c, 24);
  }
  // tail: no more issues -> tighter waits (outstanding shrinks 16/8/0)
  PROCESS(122, 16);
  PROCESS(123, 8);
  PROCESS(124, 0);

  __syncthreads();                     // all replay appends done
  if (tid == 0) ws_cnt[b] = s_spkcnt;  // written unconditionally (ws poisoned)
}

// Apply the (few hundred) recorded spikes onto the zeroed output.
__global__ void scatter_spikes(const unsigned long long* __restrict__ rec,
                               const unsigned int* __restrict__ cnt,
                               float* __restrict__ out, int cap)
{
  int b = blockIdx.x;
  unsigned int n = cnt[b];
  if ((int)n > cap) n = cap;
  for (unsigned int i = threadIdx.x; i < n; i += blockDim.x) {
    unsigned long long r = rec[(size_t)b * cap + i];
    unsigned int off = (unsigned int)(r >> 32);
    float v = __uint_as_float((unsigned int)r);
    out[(size_t)b * (T_ * N_) + off] = v;
  }
}

extern "C" void kernel_launch(void* const* d_in, const int* in_sizes, int n_in,
                              void* d_out, int out_size, void* d_ws, size_t ws_size,
                              hipStream_t stream) {
  const float* x  = (const float*)d_in[0]; // [B,T,N] input_current
  const float* w  = (const float*)d_in[1]; // [N,N] w_rec (row-major [out,in])
  const float* br = (const float*)d_in[2]; // [N] b_rec
  float* out = (float*)d_out;              // [B,T,N] spikes

  // spike-record workspace layout: [32][cap] u64 records, then [32] u32 counts
  int cap = 4096;
  size_t need = (size_t)B_ * cap * 8 + B_ * 4;
  if (ws_size < need && ws_size > 256)
    cap = (int)((ws_size - 256) / ((size_t)B_ * 8));
  unsigned long long* rec = (unsigned long long*)d_ws;
  unsigned int* cnt = (unsigned int*)((char*)d_ws + (size_t)B_ * cap * 8);

  // blocks 0..31: sequential LIF scan (1 block/batch row);
  // blocks 32..: zero the output concurrently on the remaining CUs.
  lif_fused<<<B_ + ZBLOCKS_, THREADS_, 0, stream>>>(x, w, br, out, rec, cnt, cap);
  scatter_spikes<<<B_, THREADS_, 0, stream>>>(rec, cnt, out, cap);
}

// Round 3
// 397.201 us; speedup vs baseline: 1.0207x; 1.0207x over previous
//
#include <hip/hip_runtime.h>
#include <cstdint>
#include <cstddef>

// LIF recurrent SNN, sinabs ThresholdSubtract.
//   B=32 independent batch rows -> 1 block per batch, state in registers.
//   Spikes ~4.4 sigma -> speculate "no spike in chunk", exact replay on hit.
// Round-10: R9 producer/consumer with the producer COVERAGE BUG fixed.
//   LEDGER R1..R8: every scheme needing loads in flight across the chunk
//   barrier lost to a compiler pass (R1 arrays->scratch; R2/R5 asm loads->
//   RA-opaque; R4/R8 LDS-DMA->waitcnt drains 4780cy/chunk; R6/R7 plain
//   loads->sunk to use, VGPR 68 proves no buffer lived). R9 flipped to wave
//   specialization: 4 producer waves load chunk c+1 into a depth-2 LDS ring
//   while 4 consumer waves compute chunk c; the producer eats the ~450cy
//   latency concurrently. R9 FAILED (absmax 1.0): producer wave pw loaded
//   rows {2pw,2pw+1} at lane*4 -> only floats 0..255 of each 1024-float row
//   (8KB of the 32KB slot); consumers read stale LDS -> wrong states.
//   R10: wave pw owns v4-columns [pw*64,pw*64+64) of ALL 8 rows (matches the
//   consumer read layout xring[sl][k][tid]). Producer loads are inline-asm
//   global_load_dwordx4 (volatile asm = issued back-to-back, immune to the
//   sink-to-use heuristic that would serialize 8x450cy), then ONE
//   vmcnt(0), then plain ds_writes. No memory op crosses any barrier ->
//   plain __syncthreads per chunk; replay keeps parity via 8 dummy barriers
//   on the producer side (both roles read the same s_cmask decision).
#define B_       32
#define T_       1000
#define N_       1024
#define THREADS_ 512           // 8 waves: 4 consumer (tid<256) + 4 producer
#define CWAVES_  4
#define CHUNK_   8
#define NCHUNK_  125           // 125*8 = 1000 steps
#define DEPTH_   2             // LDS ring slots (producer writes c+1, reads c)
#define SLOT_BYTES_ 32768      // CHUNK_*N_*4
#define ZBLOCKS_ 2048

typedef float v4f __attribute__((ext_vector_type(4)));

__device__ __forceinline__ v4f vmax4(v4f a, v4f b) {
  v4f r;
  r.x = fmaxf(a.x, b.x); r.y = fmaxf(a.y, b.y);
  r.z = fmaxf(a.z, b.z); r.w = fmaxf(a.w, b.w);
  return r;
}

// Inline-asm LDS read: cannot be sunk per-use by the scheduler; ordered
// manually with lgkmcnt(0) + sched_barrier(0) (rule #18). No memory clobber.
#define DSRD(dst, base, imm)                                                 \
  asm volatile("ds_read_b128 %0, %1 offset:" #imm : "=v"(dst) : "v"(base))

// Inline-asm global load: volatile asm blocks are ordered among themselves,
// so 8 of these issue back-to-back; one vmcnt(0) then covers all 8.
#define GLD(dst, p)                                                          \
  asm volatile("global_load_dwordx4 %0, %1, off" : "=v"(dst) : "v"(p))

#define SPEC_STEP(xf)                                                        \
  do {                                                                       \
    cmax = vmax4(cmax, st);                                                  \
    v4f _t = (xf) + rr;                                                      \
    st = st * 0.9f + 0.1f * _t;                                              \
    rr = brec;                                                               \
  } while (0)

// Consumer: process chunk cc from ring slot cc&1 (filled by producers before
// the previous chunk's barrier). Speculative no-spike pass; ballot exchange;
// exact replay (rare). Exactly ONE __syncthreads per chunk (+8 in replay).
#define PROCESS(cc)                                                          \
  do {                                                                       \
    unsigned _a = xb + (unsigned)(((cc) & 1) * SLOT_BYTES_)                  \
                     + ((unsigned)tid << 4);                                 \
    v4f _x0, _x1, _x2, _x3, _x4, _x5, _x6, _x7;                              \
    DSRD(_x0, _a, 0);     DSRD(_x1, _a, 4096);                               \
    DSRD(_x2, _a, 8192);  DSRD(_x3, _a, 12288);                              \
    DSRD(_x4, _a, 16384); DSRD(_x5, _a, 20480);                              \
    DSRD(_x6, _a, 24576); DSRD(_x7, _a, 28672);                              \
    asm volatile("s_waitcnt lgkmcnt(0)");                                    \
    __builtin_amdgcn_sched_barrier(0);  /* rule #18: no VALU hoist above */  \
    v4f st = state, rr = rec, cmax = state;                                  \
    SPEC_STEP(_x0); SPEC_STEP(_x1); SPEC_STEP(_x2); SPEC_STEP(_x3);          \
    SPEC_STEP(_x4); SPEC_STEP(_x5); SPEC_STEP(_x6); SPEC_STEP(_x7);          \
    float _m = fmaxf(fmaxf(cmax.x, cmax.y), fmaxf(cmax.z, cmax.w));          \
    int _any = (_m >= 1.0f);                                                 \
    const int _p = (cc) & 1;                                                 \
    unsigned long long _wm = __ballot(_any);                                 \
    if (lane == 0) s_cmask[_p][wv] = _wm;                                    \
    __syncthreads();                                                         \
    unsigned long long _ab =                                                 \
        s_cmask[_p][0] | s_cmask[_p][1] | s_cmask[_p][2] | s_cmask[_p][3];   \
    if (_ab == 0ULL) { state = st; rec = brec; }                             \
    else { replay(cc); }                                                     \
  } while (0)

__global__ __launch_bounds__(THREADS_, 1)
void lif_fused(const float* __restrict__ x, const float* __restrict__ w,
               const float* __restrict__ brec_g, float* __restrict__ out,
               unsigned long long* __restrict__ ws_rec,
               unsigned int* __restrict__ ws_cnt, int cap)
{
  // ---------------- zero path: blocks >= 32 clear the output ----------------
  if (blockIdx.x >= B_) {
    const size_t n4 = (size_t)B_ * T_ * N_ / 4;
    size_t i = (size_t)(blockIdx.x - B_) * THREADS_ + threadIdx.x;
    const size_t stride = (size_t)(gridDim.x - B_) * THREADS_;
    v4f* o4 = (v4f*)out;
    v4f z = (v4f)(0.f);
    for (; i < n4; i += stride) __builtin_nontemporal_store(z, &o4[i]);
    return;
  }

  // ---------------- lif path: blocks 0..31, one batch row each --------------
  const int b    = blockIdx.x;
  const int tid  = threadIdx.x;
  const int lane = tid & 63;
  const int wv   = tid >> 6;

  // x staging ring: 2 slots x 32KB, layout [slot][row k][v4 column 0..255].
  __shared__ v4f xring[DEPTH_][CHUNK_][N_ / 4];
  // Parity-double-buffered exchange: one barrier per chunk/step, no resets.
  __shared__ unsigned long long s_cmask[2][CWAVES_];
  __shared__ unsigned long long s_mask [2][CWAVES_];
  __shared__ v4f                s_val  [2][CWAVES_ * 64];
  __shared__ unsigned int       s_spkcnt;

  if (tid == 0) s_spkcnt = 0;   // visible to all after the prologue barrier

  const float* xg_base = x + (size_t)b * T_ * N_;

  if (wv >= CWAVES_) {
    // ------------------------- producer role ------------------------------
    // Wave pw owns v4-columns [pw*64, pw*64+64) of EVERY row: per chunk each
    // lane loads 8 rows x 16B and ds_writes them (4 waves x 64 lanes x 8 x
    // 16B = 32KB = full slot). The 8 asm loads issue back-to-back; ONE
    // vmcnt(0) eats ~450cy concurrently with consumer compute of chunk c.
    const int pw  = wv - CWAVES_;            // 0..3 = column-segment index
    const int col = (pw << 6) + lane;        // v4 column 0..255
    const float* sbase = xg_base + ((size_t)col << 2);
    {   // prologue: chunk 0 -> slot 0
      v4f a0, a1, a2, a3, a4, a5, a6, a7;
      GLD(a0, sbase + 0 * N_); GLD(a1, sbase + 1 * N_);
      GLD(a2, sbase + 2 * N_); GLD(a3, sbase + 3 * N_);
      GLD(a4, sbase + 4 * N_); GLD(a5, sbase + 5 * N_);
      GLD(a6, sbase + 6 * N_); GLD(a7, sbase + 7 * N_);
      asm volatile("s_waitcnt vmcnt(0)" ::: "memory");
      xring[0][0][col] = a0; xring[0][1][col] = a1;
      xring[0][2][col] = a2; xring[0][3][col] = a3;
      xring[0][4][col] = a4; xring[0][5][col] = a5;
      xring[0][6][col] = a6; xring[0][7][col] = a7;
    }
    __syncthreads();                      // prologue barrier (slot 0 ready)
#pragma unroll 1
    for (int c = 0; c < NCHUNK_; ++c) {
      if (c + 1 < NCHUNK_) {
        const float* pg = sbase + (size_t)(c + 1) * (CHUNK_ * N_);
        v4f a0, a1, a2, a3, a4, a5, a6, a7;
        GLD(a0, pg + 0 * N_); GLD(a1, pg + 1 * N_);
        GLD(a2, pg + 2 * N_); GLD(a3, pg + 3 * N_);
        GLD(a4, pg + 4 * N_); GLD(a5, pg + 5 * N_);
        GLD(a6, pg + 6 * N_); GLD(a7, pg + 7 * N_);
        asm volatile("s_waitcnt vmcnt(0)" ::: "memory");
        const int sl = (c + 1) & 1;
        xring[sl][0][col] = a0; xring[sl][1][col] = a1;
        xring[sl][2][col] = a2; xring[sl][3][col] = a3;
        xring[sl][4][col] = a4; xring[sl][5][col] = a5;
        xring[sl][6][col] = a6; xring[sl][7][col] = a7;
      }
      __syncthreads();                    // chunk-c barrier
      const int p = c & 1;                // mirror the consumer replay branch
      unsigned long long ab =
          s_cmask[p][0] | s_cmask[p][1] | s_cmask[p][2] | s_cmask[p][3];
      if (ab != 0ULL) {
#pragma unroll 1
        for (int k = 0; k < CHUNK_; ++k) __syncthreads();  // match replay
      }
    }
    __syncthreads();                      // epilogue barrier
    return;
  }

  // ------------------------- consumer role --------------------------------
  __builtin_amdgcn_s_setprio(1);          // T5: favor the latency-critical role
  const int n0 = tid << 2;                // this thread's 4 neurons

  // LDS byte offset of the ring base for the pinned asm ds_reads
  const unsigned xb =
      (unsigned)(uintptr_t)(__attribute__((address_space(3))) void*)xring;

  v4f state = (v4f)(0.f);
  v4f rec   = (v4f)(0.f);                 // initial carry rec = 0 (NOT b_rec)
  const v4f brec = *(const v4f*)(brec_g + n0);

  // Exact replay of chunk cc (rare): x comes from the ring slot (still valid
  // for the whole replay -- producers are parked in the matching dummy
  // barriers and only overwrite this slot after the NEXT chunk barrier).
  // Per-step spike exchange, sparse rank-1 rec update, spike records.
  auto replay = [&](int cc) {
    v4f st = state;
    v4f r  = rec;
    const int sl = cc & 1;
#pragma unroll 1
    for (int k = 0; k < CHUNK_; ++k) {
      const int q = k & 1;
      v4f xv = xring[sl][k][tid];
      float tx = xv.x + r.x, ty = xv.y + r.y, tz = xv.z + r.z, tw = xv.w + r.w;
      float ax = (st.x > 0.f) ? floorf(st.x) : 0.f;
      float ay = (st.y > 0.f) ? floorf(st.y) : 0.f;
      float az = (st.z > 0.f) ? floorf(st.z) : 0.f;
      float aw = (st.w > 0.f) ? floorf(st.w) : 0.f;
      int ms = (ax != 0.f) | (ay != 0.f) | (az != 0.f) | (aw != 0.f);
      if (ms) {
        v4f v; v.x = ax; v.y = ay; v.z = az; v.w = aw;
        s_val[q][tid] = v;
        unsigned int off = (unsigned int)((cc * CHUNK_ + k) * N_ + n0);
        float av[4] = {ax, ay, az, aw};
#pragma unroll
        for (int e = 0; e < 4; ++e) {
          if (av[e] != 0.f) {
            unsigned int idx = atomicAdd(&s_spkcnt, 1u);
            if ((int)idx < cap)
              ws_rec[(size_t)b * cap + idx] =
                  ((unsigned long long)(off + e) << 32) |
                  (unsigned long long)__float_as_uint(av[e]);
          }
        }
      }
      unsigned long long sm = __ballot(ms);
      if (lane == 0) s_mask[q][wv] = sm;
      st.x = (st.x - ax) * 0.9f + 0.1f * tx;
      st.y = (st.y - ay) * 0.9f + 0.1f * ty;
      st.z = (st.z - az) * 0.9f + 0.1f * tz;
      st.w = (st.w - aw) * 0.9f + 0.1f * tw;
      __syncthreads();                    // replay barrier (producers mirror)
      // sparse rank-1 rec update: rec[n] = b_rec[n] + sum_j act[j]*w[n][j]
      v4f racc = brec;
#pragma unroll 1
      for (int w2 = 0; w2 < CWAVES_; ++w2) {
        unsigned long long mm = s_mask[q][w2];
        while (mm) {
          int l = __builtin_ctzll(mm);
          mm &= mm - 1;
          int j = (w2 << 6) + l;
          v4f v = s_val[q][j];
          int jn = j << 2;
          if (v.x != 0.f) {
            racc.x += v.x * w[(size_t)(n0 + 0) * N_ + jn];
            racc.y += v.x * w[(size_t)(n0 + 1) * N_ + jn];
            racc.z += v.x * w[(size_t)(n0 + 2) * N_ + jn];
            racc.w += v.x * w[(size_t)(n0 + 3) * N_ + jn];
          }
          if (v.y != 0.f) {
            int j1 = jn + 1;
            racc.x += v.y * w[(size_t)(n0 + 0) * N_ + j1];
            racc.y += v.y * w[(size_t)(n0 + 1) * N_ + j1];
            racc.z += v.y * w[(size_t)(n0 + 2) * N_ + j1];
            racc.w += v.y * w[(size_t)(n0 + 3) * N_ + j1];
          }
          if (v.z != 0.f) {
            int j2 = jn + 2;
            racc.x += v.z * w[(size_t)(n0 + 0) * N_ + j2];
            racc.y += v.z * w[(size_t)(n0 + 1) * N_ + j2];
            racc.z += v.z * w[(size_t)(n0 + 2) * N_ + j2];
            racc.w += v.z * w[(size_t)(n0 + 3) * N_ + j2];
          }
          if (v.w != 0.f) {
            int j3 = jn + 3;
            racc.x += v.w * w[(size_t)(n0 + 0) * N_ + j3];
            racc.y += v.w * w[(size_t)(n0 + 1) * N_ + j3];
            racc.z += v.w * w[(size_t)(n0 + 2) * N_ + j3];
            racc.w += v.w * w[(size_t)(n0 + 3) * N_ + j3];
          }
        }
      }
      r = racc;
    }
    state = st;
    rec   = r;
  };

  __syncthreads();                        // prologue barrier (slot 0 ready)
#pragma unroll 1
  for (int c = 0; c < NCHUNK_; ++c) {
    PROCESS(c);
  }

  __syncthreads();                        // epilogue (all replay appends done)
  if (tid == 0) ws_cnt[b] = s_spkcnt;     // written unconditionally (ws poisoned)
}

// Apply the (few hundred) recorded spikes onto the zeroed output.
__global__ void scatter_spikes(const unsigned long long* __restrict__ rec,
                               const unsigned int* __restrict__ cnt,
                               float* __restrict__ out, int cap)
{
  int b = blockIdx.x;
  unsigned int n = cnt[b];
  if ((int)n > cap) n = cap;
  for (unsigned int i = threadIdx.x; i < n; i += blockDim.x) {
    unsigned long long r = rec[(size_t)b * cap + i];
    unsigned int off = (unsigned int)(r >> 32);
    float v = __uint_as_float((unsigned int)r);
    out[(size_t)b * (T_ * N_) + off] = v;
  }
}

extern "C" void kernel_launch(void* const* d_in, const int* in_sizes, int n_in,
                              void* d_out, int out_size, void* d_ws, size_t ws_size,
                              hipStream_t stream) {
  const float* x  = (const float*)d_in[0]; // [B,T,N] input_current
  const float* w  = (const float*)d_in[1]; // [N,N] w_rec (row-major [out,in])
  const float* br = (const float*)d_in[2]; // [N] b_rec
  float* out = (float*)d_out;              // [B,T,N] spikes

  // spike-record workspace layout: [32][cap] u64 records, then [32] u32 counts
  int cap = 4096;
  size_t need = (size_t)B_ * cap * 8 + B_ * 4;
  if (ws_size < need && ws_size > 256)
    cap = (int)((ws_size - 256) / ((size_t)B_ * 8));
  unsigned long long* rec = (unsigned long long*)d_ws;
  unsigned int* cnt = (unsigned int*)((char*)d_ws + (size_t)B_ * cap * 8);

  // blocks 0..31: sequential LIF scan (1 block/batch row);
  // blocks 32..: zero the output concurrently on the remaining CUs.
  lif_fused<<<B_ + ZBLOCKS_, THREADS_, 0, stream>>>(x, w, br, out, rec, cnt, cap);
  scatter_spikes<<<B_, THREADS_, 0, stream>>>(rec, cnt, out, cap);
}

// Round 4
// 326.346 us; speedup vs baseline: 1.2423x; 1.2171x over previous
//
#include <hip/hip_runtime.h>
#include <cstdint>
#include <cstddef>

// LIF recurrent SNN, sinabs ThresholdSubtract.
//   B=32 independent batch rows -> 1 block per batch, state in registers.
//   Spikes ~4.4 sigma -> speculate "no spike in chunk", exact replay on hit.
// Round-11: R10 producer/consumer + (1) guaranteed CU exclusivity and
//   (2) depth-4 ring with counted producer vmcnt.
//   LEDGER: R1..R8 -- consumer-side prefetch always defeated by a compiler
//   pass (sink-to-use / scratch / LDS-DMA drains). R10 (prod/cons, depth-2,
//   vmcnt(0) per window) = 4600cy/chunk: depth-2 gives ZERO latency
//   tolerance (wall = producer issue->complete->write each window) and LDS
//   74KB allowed a zero-path block on the same CU, its 8 waves of streaming
//   stores queueing the producer's 512 line-requests/window in the TA pipe.
//   R11 fix 1: 4-slot ring -> LDS 139KB -> HW-enforced 1 block/CU; grid =
//   256 total blocks = #CUs -> lif blocks NEVER share a CU with the zero
//   path. Fix 2: producer unroll x2 with named reg buffers A/B; window c:
//   vmcnt(8) [chunk c+2 landed, chunk c+3 still flying] -> ds_write slot
//   (c+2)&3 -> issue chunk c+4 -> barrier. 16 loads always in flight,
//   vmcnt never 0 in the loop (T3/T4) -> ~2.5 windows of latency tolerance.
//   Producer path has NO tracked VMEM (loads are asm) so __syncthreads
//   emits lgkm-only drains and leaves the asm loads in flight.
#define B_       32
#define T_       1000
#define N_       1024
#define THREADS_ 512           // 8 waves: 4 consumer (tid<256) + 4 producer
#define CWAVES_  4
#define CHUNK_   8
#define NCHUNK_  125           // 125*8 = 1000 steps
#define DEPTH_   4             // LDS ring slots
#define SLOT_BYTES_ 32768      // CHUNK_*N_*4
#define ZBLOCKS_ 224           // total grid = 256 blocks = #CUs (1 block/CU)

typedef float v4f __attribute__((ext_vector_type(4)));

__device__ __forceinline__ v4f vmax4(v4f a, v4f b) {
  v4f r;
  r.x = fmaxf(a.x, b.x); r.y = fmaxf(a.y, b.y);
  r.z = fmaxf(a.z, b.z); r.w = fmaxf(a.w, b.w);
  return r;
}

// Inline-asm LDS read: opaque to SIInsertWaitcnts; ordered manually with
// lgkmcnt(0) + sched_barrier(0) (rule #18).
#define DSRD(dst, base, imm)                                                 \
  asm volatile("ds_read_b128 %0, %1 offset:" #imm : "=v"(dst) : "v"(base))

// Inline-asm global load: volatile asm is ordered among itself and against
// the volatile vmcnt asms -> issue points are pinned; the waitcnt pass
// inserts nothing (asm is opaque), so counted vmcnt below is exact.
#define GLD(dst, p)                                                          \
  asm volatile("global_load_dwordx4 %0, %1, off" : "=v"(dst) : "v"(p))

#define VM8 asm volatile("s_waitcnt vmcnt(8)" ::: "memory")
#define VM0 asm volatile("s_waitcnt vmcnt(0)" ::: "memory")

// Issue one chunk's 8 row-loads for this producer lane (v4 column `col`).
#define GIS(b0,b1,b2,b3,b4,b5,b6,b7, cc)                                     \
  do {                                                                       \
    const float* _p = sbase + (size_t)(cc) * (CHUNK_ * N_);                  \
    GLD(b0, _p + 0 * N_); GLD(b1, _p + 1 * N_);                              \
    GLD(b2, _p + 2 * N_); GLD(b3, _p + 3 * N_);                              \
    GLD(b4, _p + 4 * N_); GLD(b5, _p + 5 * N_);                              \
    GLD(b6, _p + 6 * N_); GLD(b7, _p + 7 * N_);                              \
    __builtin_amdgcn_sched_barrier(0);  /* pin issue point */                \
  } while (0)

// Write a landed chunk from registers into its ring slot.
#define WRS(b0,b1,b2,b3,b4,b5,b6,b7, cc)                                     \
  do {                                                                       \
    const int _sl = (cc) & (DEPTH_ - 1);                                     \
    xring[_sl][0][col] = b0; xring[_sl][1][col] = b1;                        \
    xring[_sl][2][col] = b2; xring[_sl][3][col] = b3;                        \
    xring[_sl][4][col] = b4; xring[_sl][5][col] = b5;                        \
    xring[_sl][6][col] = b6; xring[_sl][7][col] = b7;                        \
  } while (0)

#define SPEC_STEP(xf)                                                        \
  do {                                                                       \
    cmax = vmax4(cmax, st);                                                  \
    v4f _t = (xf) + rr;                                                      \
    st = st * 0.9f + 0.1f * _t;                                              \
    rr = brec;                                                               \
  } while (0)

// Consumer: process chunk cc from ring slot cc&3 (written by producers two
// windows earlier). Speculative no-spike pass; ballot exchange; exact
// replay (rare). Exactly ONE __syncthreads per chunk (+8 in replay).
#define PROCESS(cc)                                                          \
  do {                                                                       \
    unsigned _a = xb + (unsigned)(((cc) & (DEPTH_ - 1)) * SLOT_BYTES_)       \
                     + ((unsigned)tid << 4);                                 \
    v4f _x0, _x1, _x2, _x3, _x4, _x5, _x6, _x7;                              \
    DSRD(_x0, _a, 0);     DSRD(_x1, _a, 4096);                               \
    DSRD(_x2, _a, 8192);  DSRD(_x3, _a, 12288);                              \
    DSRD(_x4, _a, 16384); DSRD(_x5, _a, 20480);                              \
    DSRD(_x6, _a, 24576); DSRD(_x7, _a, 28672);                              \
    asm volatile("s_waitcnt lgkmcnt(0)");                                    \
    __builtin_amdgcn_sched_barrier(0);  /* rule #18: no VALU hoist above */  \
    v4f st = state, rr = rec, cmax = state;                                  \
    SPEC_STEP(_x0); SPEC_STEP(_x1); SPEC_STEP(_x2); SPEC_STEP(_x3);          \
    SPEC_STEP(_x4); SPEC_STEP(_x5); SPEC_STEP(_x6); SPEC_STEP(_x7);          \
    float _m = fmaxf(fmaxf(cmax.x, cmax.y), fmaxf(cmax.z, cmax.w));          \
    int _any = (_m >= 1.0f);                                                 \
    const int _p = (cc) & 1;                                                 \
    unsigned long long _wm = __ballot(_any);                                 \
    if (lane == 0) s_cmask[_p][wv] = _wm;                                    \
    __syncthreads();                                                         \
    unsigned long long _ab =                                                 \
        s_cmask[_p][0] | s_cmask[_p][1] | s_cmask[_p][2] | s_cmask[_p][3];   \
    if (_ab == 0ULL) { state = st; rec = brec; }                             \
    else { replay(cc); }                                                     \
  } while (0)

__global__ __launch_bounds__(THREADS_, 1)
void lif_fused(const float* __restrict__ x, const float* __restrict__ w,
               const float* __restrict__ brec_g, float* __restrict__ out,
               unsigned long long* __restrict__ ws_rec,
               unsigned int* __restrict__ ws_cnt, int cap)
{
  // ---------------- zero path: blocks >= 32 clear the output ----------------
  if (blockIdx.x >= B_) {
    const size_t n4 = (size_t)B_ * T_ * N_ / 4;
    size_t i = (size_t)(blockIdx.x - B_) * THREADS_ + threadIdx.x;
    const size_t stride = (size_t)(gridDim.x - B_) * THREADS_;
    v4f* o4 = (v4f*)out;
    v4f z = (v4f)(0.f);
    for (; i < n4; i += stride) __builtin_nontemporal_store(z, &o4[i]);
    return;
  }

  // ---------------- lif path: blocks 0..31, one batch row each --------------
  const int b    = blockIdx.x;
  const int tid  = threadIdx.x;
  const int lane = tid & 63;
  const int wv   = tid >> 6;

  // x staging ring: 4 slots x 32KB, layout [slot][row k][v4 column 0..255].
  // 139KB total LDS -> hardware-enforced 1 block/CU (exclusivity).
  __shared__ v4f xring[DEPTH_][CHUNK_][N_ / 4];
  // Parity-double-buffered exchange: one barrier per chunk/step, no resets.
  __shared__ unsigned long long s_cmask[2][CWAVES_];
  __shared__ unsigned long long s_mask [2][CWAVES_];
  __shared__ v4f                s_val  [2][CWAVES_ * 64];
  __shared__ unsigned int       s_spkcnt;

  if (tid == 0) s_spkcnt = 0;   // visible to all after the prologue barrier

  const float* xg_base = x + (size_t)b * T_ * N_;

  if (wv >= CWAVES_) {
    // ------------------------- producer role ------------------------------
    // Wave pw owns v4-columns [pw*64, pw*64+64) of EVERY row (matches the
    // consumer read layout xring[sl][k][tid]). Unroll x2, named buffers A/B.
    // Steady state at window c (even): A = chunk c+2 in flight, B = chunk
    // c+3 in flight (16 loads outstanding). vmcnt(8) retires the oldest 8.
    const int pw  = wv - CWAVES_;            // 0..3 = column-segment index
    const int col = (pw << 6) + lane;        // v4 column 0..255
    const float* sbase = xg_base + ((size_t)col << 2);

    auto replaycheck = [&](int c) {
      const int p = c & 1;
      unsigned long long ab =
          s_cmask[p][0] | s_cmask[p][1] | s_cmask[p][2] | s_cmask[p][3];
      if (ab != 0ULL) {
#pragma unroll 1
        for (int k = 0; k < CHUNK_; ++k) __syncthreads();  // mirror replay
      }
    };

    v4f A0, A1, A2, A3, A4, A5, A6, A7;
    v4f B0, B1, B2, B3, B4, B5, B6, B7;

    // prologue: fill slots 0,1; leave chunks 2 (A) and 3 (B) in flight
    GIS(A0,A1,A2,A3,A4,A5,A6,A7, 0);
    GIS(B0,B1,B2,B3,B4,B5,B6,B7, 1);
    VM8; WRS(A0,A1,A2,A3,A4,A5,A6,A7, 0);
    GIS(A0,A1,A2,A3,A4,A5,A6,A7, 2);
    VM8; WRS(B0,B1,B2,B3,B4,B5,B6,B7, 1);
    GIS(B0,B1,B2,B3,B4,B5,B6,B7, 3);
    __syncthreads();                      // prologue barrier (slots 0,1 ready)

#pragma unroll 1
    for (int c = 0; c < NCHUNK_ - 1; c += 2) {   // windows c, c+1; c even
      // ---- window c: write A (chunk c+2), refill A <- chunk c+4 ----
      if (c <= NCHUNK_ - 5) {                    // c <= 120
        VM8; WRS(A0,A1,A2,A3,A4,A5,A6,A7, c + 2);
        GIS(A0,A1,A2,A3,A4,A5,A6,A7, c + 4);
      } else {                                   // c == 122: last write, drain
        VM0; WRS(A0,A1,A2,A3,A4,A5,A6,A7, c + 2);
      }
      __syncthreads();                    // barrier c
      replaycheck(c);
      // ---- window c+1: write B (chunk c+3), refill B <- chunk c+5 ----
      if (c <= NCHUNK_ - 5) {                    // c <= 120 -> chunk c+3 valid
        VM8; WRS(B0,B1,B2,B3,B4,B5,B6,B7, c + 3);
        if (c <= NCHUNK_ - 7)                    // c <= 118 -> chunk c+5 valid
          GIS(B0,B1,B2,B3,B4,B5,B6,B7, c + 5);
      }
      __syncthreads();                    // barrier c+1
      replaycheck(c + 1);
    }
    // window 124: nothing to write/issue
    __syncthreads();                      // barrier 124
    replaycheck(NCHUNK_ - 1);
    __syncthreads();                      // epilogue barrier
    return;
  }

  // ------------------------- consumer role --------------------------------
  __builtin_amdgcn_s_setprio(1);          // T5: favor the latency-critical role
  const int n0 = tid << 2;                // this thread's 4 neurons

  // LDS byte offset of the ring base for the pinned asm ds_reads
  const unsigned xb =
      (unsigned)(uintptr_t)(__attribute__((address_space(3))) void*)xring;

  v4f state = (v4f)(0.f);
  v4f rec   = (v4f)(0.f);                 // initial carry rec = 0 (NOT b_rec)
  const v4f brec = *(const v4f*)(brec_g + n0);

  // Exact replay of chunk cc (rare): x comes from ring slot cc&3 (valid until
  // chunk c+4 is written in window c+2; producers are parked in the matching
  // dummy barriers during replay). Per-step spike exchange, sparse rank-1
  // rec update, spike records.
  auto replay = [&](int cc) {
    v4f st = state;
    v4f r  = rec;
    const int sl = cc & (DEPTH_ - 1);
#pragma unroll 1
    for (int k = 0; k < CHUNK_; ++k) {
      const int q = k & 1;
      v4f xv = xring[sl][k][tid];
      float tx = xv.x + r.x, ty = xv.y + r.y, tz = xv.z + r.z, tw = xv.w + r.w;
      float ax = (st.x > 0.f) ? floorf(st.x) : 0.f;
      float ay = (st.y > 0.f) ? floorf(st.y) : 0.f;
      float az = (st.z > 0.f) ? floorf(st.z) : 0.f;
      float aw = (st.w > 0.f) ? floorf(st.w) : 0.f;
      int ms = (ax != 0.f) | (ay != 0.f) | (az != 0.f) | (aw != 0.f);
      if (ms) {
        v4f v; v.x = ax; v.y = ay; v.z = az; v.w = aw;
        s_val[q][tid] = v;
        unsigned int off = (unsigned int)((cc * CHUNK_ + k) * N_ + n0);
        float av[4] = {ax, ay, az, aw};
#pragma unroll
        for (int e = 0; e < 4; ++e) {
          if (av[e] != 0.f) {
            unsigned int idx = atomicAdd(&s_spkcnt, 1u);
            if ((int)idx < cap)
              ws_rec[(size_t)b * cap + idx] =
                  ((unsigned long long)(off + e) << 32) |
                  (unsigned long long)__float_as_uint(av[e]);
          }
        }
      }
      unsigned long long sm = __ballot(ms);
      if (lane == 0) s_mask[q][wv] = sm;
      st.x = (st.x - ax) * 0.9f + 0.1f * tx;
      st.y = (st.y - ay) * 0.9f + 0.1f * ty;
      st.z = (st.z - az) * 0.9f + 0.1f * tz;
      st.w = (st.w - aw) * 0.9f + 0.1f * tw;
      __syncthreads();                    // replay barrier (producers mirror)
      // sparse rank-1 rec update: rec[n] = b_rec[n] + sum_j act[j]*w[n][j]
      v4f racc = brec;
#pragma unroll 1
      for (int w2 = 0; w2 < CWAVES_; ++w2) {
        unsigned long long mm = s_mask[q][w2];
        while (mm) {
          int l = __builtin_ctzll(mm);
          mm &= mm - 1;
          int j = (w2 << 6) + l;
          v4f v = s_val[q][j];
          int jn = j << 2;
          if (v.x != 0.f) {
            racc.x += v.x * w[(size_t)(n0 + 0) * N_ + jn];
            racc.y += v.x * w[(size_t)(n0 + 1) * N_ + jn];
            racc.z += v.x * w[(size_t)(n0 + 2) * N_ + jn];
            racc.w += v.x * w[(size_t)(n0 + 3) * N_ + jn];
          }
          if (v.y != 0.f) {
            int j1 = jn + 1;
            racc.x += v.y * w[(size_t)(n0 + 0) * N_ + j1];
            racc.y += v.y * w[(size_t)(n0 + 1) * N_ + j1];
            racc.z += v.y * w[(size_t)(n0 + 2) * N_ + j1];
            racc.w += v.y * w[(size_t)(n0 + 3) * N_ + j1];
          }
          if (v.z != 0.f) {
            int j2 = jn + 2;
            racc.x += v.z * w[(size_t)(n0 + 0) * N_ + j2];
            racc.y += v.z * w[(size_t)(n0 + 1) * N_ + j2];
            racc.z += v.z * w[(size_t)(n0 + 2) * N_ + j2];
            racc.w += v.z * w[(size_t)(n0 + 3) * N_ + j2];
          }
          if (v.w != 0.f) {
            int j3 = jn + 3;
            racc.x += v.w * w[(size_t)(n0 + 0) * N_ + j3];
            racc.y += v.w * w[(size_t)(n0 + 1) * N_ + j3];
            racc.z += v.w * w[(size_t)(n0 + 2) * N_ + j3];
            racc.w += v.w * w[(size_t)(n0 + 3) * N_ + j3];
          }
        }
      }
      r = racc;
    }
    state = st;
    rec   = r;
  };

  __syncthreads();                        // prologue barrier (slots 0,1 ready)
#pragma unroll 1
  for (int c = 0; c < NCHUNK_; ++c) {
    PROCESS(c);
  }

  __syncthreads();                        // epilogue (all replay appends done)
  if (tid == 0) ws_cnt[b] = s_spkcnt;     // written unconditionally (ws poisoned)
}

// Apply the (few hundred) recorded spikes onto the zeroed output.
__global__ void scatter_spikes(const unsigned long long* __restrict__ rec,
                               const unsigned int* __restrict__ cnt,
                               float* __restrict__ out, int cap)
{
  int b = blockIdx.x;
  unsigned int n = cnt[b];
  if ((int)n > cap) n = cap;
  for (unsigned int i = threadIdx.x; i < n; i += blockDim.x) {
    unsigned long long r = rec[(size_t)b * cap + i];
    unsigned int off = (unsigned int)(r >> 32);
    float v = __uint_as_float((unsigned int)r);
    out[(size_t)b * (T_ * N_) + off] = v;
  }
}

extern "C" void kernel_launch(void* const* d_in, const int* in_sizes, int n_in,
                              void* d_out, int out_size, void* d_ws, size_t ws_size,
                              hipStream_t stream) {
  const float* x  = (const float*)d_in[0]; // [B,T,N] input_current
  const float* w  = (const float*)d_in[1]; // [N,N] w_rec (row-major [out,in])
  const float* br = (const float*)d_in[2]; // [N] b_rec
  float* out = (float*)d_out;              // [B,T,N] spikes

  // spike-record workspace layout: [32][cap] u64 records, then [32] u32 counts
  int cap = 4096;
  size_t need = (size_t)B_ * cap * 8 + B_ * 4;
  if (ws_size < need && ws_size > 256)
    cap = (int)((ws_size - 256) / ((size_t)B_ * 8));
  unsigned long long* rec = (unsigned long long*)d_ws;
  unsigned int* cnt = (unsigned int*)((char*)d_ws + (size_t)B_ * cap * 8);

  // blocks 0..31: sequential LIF scan (1 block/batch row, exclusive CU);
  // blocks 32..255: zero the output on the remaining CUs (1 block/CU).
  lif_fused<<<B_ + ZBLOCKS_, THREADS_, 0, stream>>>(x, w, br, out, rec, cnt, cap);
  scatter_spikes<<<B_, THREADS_, 0, stream>>>(rec, cnt, out, cap);
}